// Round 3
// baseline (578.819 us; speedup 1.0000x reference)
//
#include <hip/hip_runtime.h>

typedef unsigned short u16;
typedef __attribute__((ext_vector_type(8))) short short8;
typedef __attribute__((ext_vector_type(4))) float floatx4;

#define NN_TOT 135168   // 4096 * 33

// ---- compile-time skeleton (from SKELETON_EDGES, incl. self-loops) ----
static constexpr int NBCNT[33] = {2,2,2,2,2,2,2,1,1,1,1,3,3,2,2,4,4,2,2,2,2,1,1,3,3,2,2,3,3,2,2,2,2};
static constexpr int NBR[33][4] = {
 {1,4,0,0},{0,2,0,0},{1,3,0,0},{2,7,0,0},{0,5,0,0},{4,6,0,0},{5,8,0,0},
 {3,0,0,0},{6,0,0,0},{10,0,0,0},{9,0,0,0},
 {12,13,23,0},{11,14,24,0},{11,15,0,0},{12,16,0,0},
 {13,17,19,21},{14,18,20,22},
 {15,19,0,0},{16,20,0,0},{15,17,0,0},{16,18,0,0},{15,0,0,0},{16,0,0,0},
 {11,24,25,0},{12,23,26,0},{23,27,0,0},{24,28,0,0},
 {25,29,31,0},{26,30,32,0},{27,31,0,0},{28,32,0,0},{29,27,0,0},{30,28,0,0}};
static constexpr float R2 = 0.70710678f, R3 = 0.57735027f, R4 = 0.5f, R5 = 0.44721360f;
static constexpr float DINV[33] = {R3,R3,R3,R3,R3,R3,R3, R2,R2,R2,R2, R4,R4, R3,R3, R5,R5,
                                   R3,R3,R3,R3, R2,R2, R4,R4, R3,R3, R4,R4, R3,R3,R3,R3};

__device__ __forceinline__ float bf2f(u16 u) {
  unsigned int v = ((unsigned int)u) << 16; float f; __builtin_memcpy(&f, &v, 4); return f;
}
__device__ __forceinline__ u16 f2bf(float f) {
  unsigned int u; __builtin_memcpy(&u, &f, 4);
  return (u16)((u + 0x7fffu + ((u >> 16) & 1u)) >> 16);
}
// dtype-flexible input read: isbf ? bf16[i] : f32[i]
__device__ __forceinline__ float ldin(const void* p, int i, int isbf) {
  return isbf ? bf2f(((const u16*)p)[i]) : ((const float*)p)[i];
}
__device__ __forceinline__ void gload_lds16(const u16* g, u16* l) {
  __builtin_amdgcn_global_load_lds((const __attribute__((address_space(1))) unsigned int*)g,
                                   (__attribute__((address_space(3))) unsigned int*)l, 16, 0, 0);
}

// ---- dtype detector: even-indexed u16s of bf16 N(0,1) data have exponent
// field in [118,130] ~99.8% of the time; fp32 low-mantissa halves ~5%. ----
__global__ __launch_bounds__(256) void detect_kernel(const u16* __restrict__ x,
                                                     int* __restrict__ flag)
{
  __shared__ int cnt[256];
  const int t = threadIdx.x;
  int c = 0;
  for (int j = 0; j < 16; ++j) {
    u16 u = x[(t*16 + j)*2];
    int e = (u >> 7) & 0xFF;
    c += (e >= 118 && e <= 130) ? 1 : 0;
  }
  cnt[t] = c;
  __syncthreads();
  if (t == 0) {
    int s = 0;
    for (int i = 0; i < 256; ++i) s += cnt[i];
    *flag = (s > 2048) ? 1 : 0;   // 1 = bf16 inputs, 0 = fp32 inputs
  }
}

// ---- W transpose + canonicalize to bf16: Wt[n][k] = W[k][n] ----
__global__ __launch_bounds__(256) void transpose_kernel(const void* __restrict__ w0,
    const void* __restrict__ w1, const void* __restrict__ w2, u16* __restrict__ Wt,
    const int* __restrict__ flag)
{
  const void* W = blockIdx.x == 0 ? w0 : (blockIdx.x == 1 ? w1 : w2);
  u16* O = Wt + (size_t)blockIdx.x * 65536;
  const int t = threadIdx.x;
  const int isbf = *flag;
  if (isbf) {
    const u16* Wb = (const u16*)W;
    for (int k = 0; k < 256; ++k) O[t*256 + k] = Wb[k*256 + t];
  } else {
    const float* Wf = (const float*)W;
    for (int k = 0; k < 256; ++k) O[t*256 + k] = f2bf(Wf[k*256 + t]);
  }
}

// ---- init: wq = wh@wc, bq = bh@wc + bc, zero stat replicas ----
__global__ __launch_bounds__(256) void init_kernel(const void* __restrict__ wh,
    const void* __restrict__ bh, const void* __restrict__ wc, const void* __restrict__ bc,
    float* __restrict__ wq, float* __restrict__ bq, float* __restrict__ repl,
    const int* __restrict__ flag)
{
  const int idx = blockIdx.x*256 + threadIdx.x;
  for (int i = idx; i < 3*64*512; i += 64*256) repl[i] = 0.f;
  if (blockIdx.x == 0) {
    const int t = threadIdx.x;
    const int isbf = *flag;
    float a0=0.f, a1=0.f, a2=0.f, a3=0.f;
    for (int k = 0; k < 256; ++k) {
      float w = ldin(wh, t*256 + k, isbf);
      a0 += w*ldin(wc, k*4+0, isbf); a1 += w*ldin(wc, k*4+1, isbf);
      a2 += w*ldin(wc, k*4+2, isbf); a3 += w*ldin(wc, k*4+3, isbf);
    }
    wq[t*4+0]=a0; wq[t*4+1]=a1; wq[t*4+2]=a2; wq[t*4+3]=a3;
    if (t < 4) {
      float s = ldin(bc, t, isbf);
      for (int k = 0; k < 256; ++k) s += ldin(bh, k, isbf) * ldin(wc, k*4+t, isbf);
      bq[t] = s;
    }
  }
}

// ---- MFMA GEMM: T = act(Ag) @ W   (M=135168, N=K=256) ----
// ACT==0: identity, Ag = external x (dtype per flag), out-of-place -> T
// ACT==1: BN-ReLU scale/shift, Ag/T internal bf16, IN-PLACE safe (block reads
//         only its own 128-row stripe, writes it only in the epilogue).
template<int ACT>
__global__ __launch_bounds__(256, 2) void gemm_kernel(
    const void* __restrict__ Ag, const u16* __restrict__ Bt,
    const float* __restrict__ fscale, const float* __restrict__ fshift,
    u16* __restrict__ T, const int* __restrict__ flag)
{
  __shared__ __align__(16) u16 sA[128*32];   // [m][k] bf16
  __shared__ __align__(16) u16 sB[256*32];   // [n][k] bf16 (W pre-transposed)
  const int tid = threadIdx.x;
  const int lane = tid & 63, wid = tid >> 6;
  const int wm = wid >> 1, wn = wid & 1;
  const size_t m0 = (size_t)blockIdx.x * 128;
  const int isbf = (ACT == 0) ? *flag : 1;

  floatx4 acc[4][8];
#pragma unroll
  for (int i = 0; i < 4; ++i)
#pragma unroll
    for (int j = 0; j < 8; ++j) acc[i][j] = (floatx4){0.f, 0.f, 0.f, 0.f};

  const int r0 = tid >> 2;          // 0..63 (manual staging row)
  const int c8 = (tid & 3) * 8;     // 0,8,16,24 (manual staging col group)
  const int lr = lane >> 2;         // 0..15 (lds-dma row in 16-row group)
  const int lc = (lane & 3) * 8;    // lds-dma col group (shorts)
  const int fr = lane & 15, q = lane >> 4;

  for (int kc = 0; kc < 8; ++kc) {
    const int k0 = kc * 32;
    __syncthreads();
    if (ACT == 0) {
      if (isbf) {
        const u16* Ab = (const u16*)Ag;
#pragma unroll
        for (int i = 0; i < 2; ++i)
          gload_lds16(Ab + (m0 + wid*32 + i*16 + lr)*256 + k0 + lc,
                      sA + (wid*32 + i*16)*32);
      } else {
        const float* Af = (const float*)Ag;
#pragma unroll
        for (int rr = 0; rr < 2; ++rr) {
          const int r = r0 + rr*64;
          float4 p0 = *(const float4*)(Af + (m0 + r)*256 + k0 + c8);
          float4 p1 = *(const float4*)(Af + (m0 + r)*256 + k0 + c8 + 4);
          u16 ov[8];
          ov[0]=f2bf(p0.x); ov[1]=f2bf(p0.y); ov[2]=f2bf(p0.z); ov[3]=f2bf(p0.w);
          ov[4]=f2bf(p1.x); ov[5]=f2bf(p1.y); ov[6]=f2bf(p1.z); ov[7]=f2bf(p1.w);
          *(uint4*)(sA + r*32 + c8) = *(const uint4*)ov;
        }
      }
    } else {
      const u16* Ab = (const u16*)Ag;
      float scv[8], shv[8];
#pragma unroll
      for (int j = 0; j < 8; ++j) { scv[j] = fscale[k0 + c8 + j]; shv[j] = fshift[k0 + c8 + j]; }
#pragma unroll
      for (int rr = 0; rr < 2; ++rr) {
        const int r = r0 + rr*64;
        uint4 pk = *(const uint4*)(Ab + (m0 + r)*256 + k0 + c8);
        const u16* us = (const u16*)&pk;
        u16 ov[8];
#pragma unroll
        for (int j = 0; j < 8; ++j) {
          float f = bf2f(us[j]);
          f = fmaxf(0.f, fmaf(f, scv[j], shv[j]));
          ov[j] = f2bf(f);
        }
        *(uint4*)(sA + r*32 + c8) = *(const uint4*)ov;
      }
    }
#pragma unroll
    for (int i = 0; i < 4; ++i)
      gload_lds16(Bt + (wid*64 + i*16 + lr)*256 + k0 + lc,
                  sB + (wid*64 + i*16)*32);
    __syncthreads();

    short8 a[4], b[8];
#pragma unroll
    for (int mf = 0; mf < 4; ++mf) a[mf] = *(const short8*)(sA + (wm*64 + mf*16 + fr)*32 + q*8);
#pragma unroll
    for (int nf = 0; nf < 8; ++nf) b[nf] = *(const short8*)(sB + (wn*128 + nf*16 + fr)*32 + q*8);
#pragma unroll
    for (int mf = 0; mf < 4; ++mf)
#pragma unroll
      for (int nf = 0; nf < 8; ++nf)
        acc[mf][nf] = __builtin_amdgcn_mfma_f32_16x16x32_bf16(a[mf], b[nf], acc[mf][nf], 0, 0, 0);
  }

#pragma unroll
  for (int mf = 0; mf < 4; ++mf)
#pragma unroll
    for (int nf = 0; nf < 8; ++nf)
#pragma unroll
      for (int r = 0; r < 4; ++r) {
        const size_t row = m0 + wm*64 + mf*16 + q*4 + r;
        const int col = wn*128 + nf*16 + fr;
        T[row*256 + col] = f2bf(acc[mf][nf][r]);
      }
}

// ---- per-graph aggregation H = Ahat @ T + b (IN-PLACE: H == T), BN stats ----
__global__ __launch_bounds__(256) void agg_kernel(const u16* __restrict__ T,
    const void* __restrict__ bias, u16* __restrict__ H, float* __restrict__ repl,
    const int* __restrict__ flag)
{
  const int g = blockIdx.x, c = threadIdx.x;
  const int isbf = *flag;
  const u16* tg = T + (size_t)g * (33*256);
  u16* hg = H + (size_t)g * (33*256);
  float acc[33];
#pragma unroll
  for (int d = 0; d < 33; ++d) acc[d] = 0.f;
#pragma unroll
  for (int s = 0; s < 33; ++s) {
    float v = bf2f(tg[s*256 + c]) * DINV[s];
    acc[s] += v;                          // self loop
#pragma unroll
    for (int i = 0; i < NBCNT[s]; ++i) acc[NBR[s][i]] += v;
  }
  const float bv = ldin(bias, c, isbf);
  float s1 = 0.f, s2 = 0.f;
#pragma unroll
  for (int d = 0; d < 33; ++d) {
    float o = fmaf(acc[d], DINV[d], bv);
    hg[d*256 + c] = f2bf(o);
    s1 += o; s2 += o*o;
  }
  float* r1 = repl + (size_t)(g & 63) * 512;
  atomicAdd(r1 + c, s1);
  atomicAdd(r1 + 256 + c, s2);
}

// ---- finalize BN stats -> scale/shift ----
__global__ __launch_bounds__(256) void statfin_kernel(const float* __restrict__ repl,
    const void* __restrict__ gamma, const void* __restrict__ beta, float* __restrict__ fs,
    const int* __restrict__ flag)
{
  const int c = threadIdx.x;
  const int isbf = *flag;
  float s1 = 0.f, s2 = 0.f;
  for (int r = 0; r < 64; ++r) { s1 += repl[r*512 + c]; s2 += repl[r*512 + 256 + c]; }
  const float inv = 1.f / (float)NN_TOT;
  const float mu = s1 * inv;
  const float var = s2 * inv - mu*mu;
  const float rs = rsqrtf(var + 1e-5f);
  const float sc = rs * ldin(gamma, c, isbf);
  fs[c] = sc;
  fs[256 + c] = ldin(beta, c, isbf) - mu * sc;
}

// ---- fused layer3 + mean-pool + classifier ----
__global__ __launch_bounds__(256) void final_kernel(const u16* __restrict__ H,
    const float* __restrict__ fs, const float* __restrict__ wq,
    const float* __restrict__ bq, void* __restrict__ outp,
    const int* __restrict__ flag)
{
  const int g = blockIdx.x, c = threadIdx.x;
  const int isbf = *flag;
  const float sc = fs[c], sh = fs[256 + c];
  const u16* hg = H + (size_t)g * (33*256);
  float v = 0.f;
#pragma unroll
  for (int s = 0; s < 33; ++s) {
    float a = DINV[s];
#pragma unroll
    for (int i = 0; i < NBCNT[s]; ++i) a += DINV[NBR[s][i]];
    const float w = DINV[s] * a * (1.f/33.f);   // column-sum of Ahat / 33
    float x = bf2f(hg[s*256 + c]);
    x = fmaxf(0.f, fmaf(x, sc, sh));
    v += w * x;
  }
  float p0 = v*wq[c*4+0], p1 = v*wq[c*4+1], p2 = v*wq[c*4+2], p3 = v*wq[c*4+3];
#pragma unroll
  for (int off = 32; off; off >>= 1) {
    p0 += __shfl_xor(p0, off);
    p1 += __shfl_xor(p1, off);
    p2 += __shfl_xor(p2, off);
    p3 += __shfl_xor(p3, off);
  }
  __shared__ float sred[4][4];
  const int lane = c & 63, wid = c >> 6;
  if (lane == 0) { sred[wid][0]=p0; sred[wid][1]=p1; sred[wid][2]=p2; sred[wid][3]=p3; }
  __syncthreads();
  if (c < 4) {
    float r = sred[0][c] + sred[1][c] + sred[2][c] + sred[3][c] + bq[c];
    if (isbf) ((u16*)outp)[(size_t)g*4 + c] = f2bf(r);
    else      ((float*)outp)[(size_t)g*4 + c] = r;
  }
}

extern "C" void kernel_launch(void* const* d_in, const int* in_sizes, int n_in,
                              void* d_out, int out_size, void* d_ws, size_t ws_size,
                              hipStream_t stream)
{
  const void* x   = d_in[0];
  const void* w0  = d_in[1];
  const void* b0  = d_in[2];
  const void* g0  = d_in[3];
  const void* be0 = d_in[4];
  const void* w1  = d_in[5];
  const void* b1  = d_in[6];
  const void* g1  = d_in[7];
  const void* be1 = d_in[8];
  const void* w2  = d_in[9];
  const void* b2  = d_in[10];
  const void* g2  = d_in[11];
  const void* be2 = d_in[12];
  const void* wh  = d_in[13];
  const void* bh  = d_in[14];
  const void* wc  = d_in[15];
  const void* bc  = d_in[16];

  // Workspace: 66.8 MB total.
  char* ws = (char*)d_ws;
  float* wq   = (float*)(ws + 0);          // 1024 f
  float* bq   = (float*)(ws + 4096);       // 4 f
  float* fs   = (float*)(ws + 4608);       // 3 * 512 f
  int*   flag = (int*)  (ws + 12288);      // dtype flag
  float* repl = (float*)(ws + 16384);      // 3 * 64 * 512 f
  u16*   Wt   = (u16*)  (ws + 409600);     // 3 * 65536 bf16
  u16*   A    = (u16*)  (ws + 802816);     // 135168*256 bf16 (ends at 70,008,832)
  (void)in_sizes; (void)n_in; (void)out_size; (void)ws_size;

  detect_kernel<<<1, 256, 0, stream>>>((const u16*)x, flag);
  transpose_kernel<<<3, 256, 0, stream>>>(w0, w1, w2, Wt, flag);
  init_kernel<<<64, 256, 0, stream>>>(wh, bh, wc, bc, wq, bq, repl, flag);

  // layer 0
  gemm_kernel<0><<<1056, 256, 0, stream>>>(x, Wt, nullptr, nullptr, A, flag);
  agg_kernel<<<4096, 256, 0, stream>>>(A, b0, A, repl, flag);
  statfin_kernel<<<1, 256, 0, stream>>>(repl, g0, be0, fs, flag);
  // layer 1 (in-place GEMM)
  gemm_kernel<1><<<1056, 256, 0, stream>>>(A, Wt + 65536, fs, fs + 256, A, flag);
  agg_kernel<<<4096, 256, 0, stream>>>(A, b1, A, repl + 32768, flag);
  statfin_kernel<<<1, 256, 0, stream>>>(repl + 32768, g1, be1, fs + 512, flag);
  // layer 2 (in-place GEMM)
  gemm_kernel<1><<<1056, 256, 0, stream>>>(A, Wt + 131072, fs + 512, fs + 768, A, flag);
  agg_kernel<<<4096, 256, 0, stream>>>(A, b2, A, repl + 65536, flag);
  statfin_kernel<<<1, 256, 0, stream>>>(repl + 65536, g2, be2, fs + 1024, flag);
  // layer 3 + pool + classifier (folded)
  final_kernel<<<4096, 256, 0, stream>>>(A, fs + 1024, wq, bq, d_out, flag);
}

// Round 4
// 459.862 us; speedup vs baseline: 1.2587x; 1.2587x over previous
//
#include <hip/hip_runtime.h>

typedef unsigned short u16;
typedef __attribute__((ext_vector_type(8))) short short8;
typedef __attribute__((ext_vector_type(4))) float floatx4;

#define NN_TOT 135168   // 4096 * 33

// ---- compile-time skeleton (from SKELETON_EDGES, incl. self-loops) ----
static constexpr int NBCNT[33] = {2,2,2,2,2,2,2,1,1,1,1,3,3,2,2,4,4,2,2,2,2,1,1,3,3,2,2,3,3,2,2,2,2};
static constexpr int NBR[33][4] = {
 {1,4,0,0},{0,2,0,0},{1,3,0,0},{2,7,0,0},{0,5,0,0},{4,6,0,0},{5,8,0,0},
 {3,0,0,0},{6,0,0,0},{10,0,0,0},{9,0,0,0},
 {12,13,23,0},{11,14,24,0},{11,15,0,0},{12,16,0,0},
 {13,17,19,21},{14,18,20,22},
 {15,19,0,0},{16,20,0,0},{15,17,0,0},{16,18,0,0},{15,0,0,0},{16,0,0,0},
 {11,24,25,0},{12,23,26,0},{23,27,0,0},{24,28,0,0},
 {25,29,31,0},{26,30,32,0},{27,31,0,0},{28,32,0,0},{29,27,0,0},{30,28,0,0}};
static constexpr float R2 = 0.70710678f, R3 = 0.57735027f, R4 = 0.5f, R5 = 0.44721360f;
static constexpr float DINV[33] = {R3,R3,R3,R3,R3,R3,R3, R2,R2,R2,R2, R4,R4, R3,R3, R5,R5,
                                   R3,R3,R3,R3, R2,R2, R4,R4, R3,R3, R4,R4, R3,R3,R3,R3};

__device__ __forceinline__ float bf2f(u16 u) {
  unsigned int v = ((unsigned int)u) << 16; float f; __builtin_memcpy(&f, &v, 4); return f;
}
__device__ __forceinline__ u16 f2bf(float f) {
  unsigned int u; __builtin_memcpy(&u, &f, 4);
  return (u16)((u + 0x7fffu + ((u >> 16) & 1u)) >> 16);
}
// dtype-flexible input read: isbf ? bf16[i] : f32[i]
__device__ __forceinline__ float ldin(const void* p, int i, int isbf) {
  return isbf ? bf2f(((const u16*)p)[i]) : ((const float*)p)[i];
}
__device__ __forceinline__ void gload_lds16(const u16* g, u16* l) {
  __builtin_amdgcn_global_load_lds((const __attribute__((address_space(1))) unsigned int*)g,
                                   (__attribute__((address_space(3))) unsigned int*)l, 16, 0, 0);
}

// ---- dtype detector (unchanged) ----
__global__ __launch_bounds__(256) void detect_kernel(const u16* __restrict__ x,
                                                     int* __restrict__ flag)
{
  __shared__ int cnt[256];
  const int t = threadIdx.x;
  int c = 0;
  for (int j = 0; j < 16; ++j) {
    u16 u = x[(t*16 + j)*2];
    int e = (u >> 7) & 0xFF;
    c += (e >= 118 && e <= 130) ? 1 : 0;
  }
  cnt[t] = c;
  __syncthreads();
  if (t == 0) {
    int s = 0;
    for (int i = 0; i < 256; ++i) s += cnt[i];
    *flag = (s > 2048) ? 1 : 0;   // 1 = bf16 inputs, 0 = fp32 inputs
  }
}

// ---- W transpose + canonicalize to bf16: Wt[n][k] = W[k][n] ----
// 48 blocks: 16 per matrix, 16 output rows per block; coalesced writes.
__global__ __launch_bounds__(256) void transpose_kernel(const void* __restrict__ w0,
    const void* __restrict__ w1, const void* __restrict__ w2, u16* __restrict__ Wt,
    const int* __restrict__ flag)
{
  const int m = blockIdx.x >> 4;
  const int nb = (blockIdx.x & 15) * 16;
  const void* W = m == 0 ? w0 : (m == 1 ? w1 : w2);
  u16* O = Wt + (size_t)m * 65536;
  const int t = threadIdx.x;
  const int lane = t & 63, wv = t >> 6;
  const int isbf = *flag;
  if (isbf) {
    const u16* Wb = (const u16*)W;
#pragma unroll
    for (int nn = 0; nn < 4; ++nn) {
      const int n = nb + nn*4 + wv;
#pragma unroll
      for (int j = 0; j < 4; ++j) {
        const int k = lane + 64*j;
        O[n*256 + k] = Wb[k*256 + n];
      }
    }
  } else {
    const float* Wf = (const float*)W;
#pragma unroll
    for (int nn = 0; nn < 4; ++nn) {
      const int n = nb + nn*4 + wv;
#pragma unroll
      for (int j = 0; j < 4; ++j) {
        const int k = lane + 64*j;
        O[n*256 + k] = f2bf(Wf[k*256 + n]);
      }
    }
  }
}

// ---- init: wq = wh@wc, bq = bh@wc + bc, zero stat replicas ----
// 65 blocks: blocks 0..63 -> 4 wq rows each (lane-split K + shfl reduce);
// block 64 -> bq. repl zeroing spread over all blocks.
__global__ __launch_bounds__(256) void init_kernel(const void* __restrict__ wh,
    const void* __restrict__ bh, const void* __restrict__ wc, const void* __restrict__ bc,
    float* __restrict__ wq, float* __restrict__ bq, float* __restrict__ repl,
    const int* __restrict__ flag)
{
  const int idx = blockIdx.x*256 + threadIdx.x;
  for (int i = idx; i < 3*64*512; i += 65*256) repl[i] = 0.f;
  const int isbf = *flag;
  const int t = threadIdx.x;
  const int lane = t & 63;
  if (blockIdx.x < 64) {
    const int r = blockIdx.x*4 + (t >> 6);    // wq row, one per wave
    float a0=0.f, a1=0.f, a2=0.f, a3=0.f;
#pragma unroll
    for (int j = 0; j < 4; ++j) {
      const int k = lane + 64*j;
      const float w = ldin(wh, r*256 + k, isbf);
      a0 += w*ldin(wc, k*4+0, isbf); a1 += w*ldin(wc, k*4+1, isbf);
      a2 += w*ldin(wc, k*4+2, isbf); a3 += w*ldin(wc, k*4+3, isbf);
    }
#pragma unroll
    for (int off = 32; off; off >>= 1) {
      a0 += __shfl_xor(a0, off); a1 += __shfl_xor(a1, off);
      a2 += __shfl_xor(a2, off); a3 += __shfl_xor(a3, off);
    }
    if (lane == 0) { wq[r*4+0]=a0; wq[r*4+1]=a1; wq[r*4+2]=a2; wq[r*4+3]=a3; }
  } else if (t < 64) {
    float s0=0.f, s1=0.f, s2=0.f, s3=0.f;
#pragma unroll
    for (int j = 0; j < 4; ++j) {
      const int k = lane + 64*j;
      const float b = ldin(bh, k, isbf);
      s0 += b*ldin(wc, k*4+0, isbf); s1 += b*ldin(wc, k*4+1, isbf);
      s2 += b*ldin(wc, k*4+2, isbf); s3 += b*ldin(wc, k*4+3, isbf);
    }
#pragma unroll
    for (int off = 32; off; off >>= 1) {
      s0 += __shfl_xor(s0, off); s1 += __shfl_xor(s1, off);
      s2 += __shfl_xor(s2, off); s3 += __shfl_xor(s3, off);
    }
    if (lane == 0) {
      bq[0] = s0 + ldin(bc, 0, isbf); bq[1] = s1 + ldin(bc, 1, isbf);
      bq[2] = s2 + ldin(bc, 2, isbf); bq[3] = s3 + ldin(bc, 3, isbf);
    }
  }
}

// ---- MFMA GEMM: T = act(Ag) @ W   (M=135168, N=K=256) ----
// ACT==0: identity, Ag = external x (dtype per flag), out-of-place -> T
// ACT==1: BN-ReLU scale/shift, Ag/T internal bf16, IN-PLACE safe (block reads
//         only its own 128-row stripe, writes it only in the epilogue).
template<int ACT>
__global__ __launch_bounds__(256, 2) void gemm_kernel(
    const void* __restrict__ Ag, const u16* __restrict__ Bt,
    const float* __restrict__ fscale, const float* __restrict__ fshift,
    u16* __restrict__ T, const int* __restrict__ flag)
{
  __shared__ __align__(16) u16 sA[128*32];   // [m][k] bf16
  __shared__ __align__(16) u16 sB[256*32];   // [n][k] bf16 (W pre-transposed)
  const int tid = threadIdx.x;
  const int lane = tid & 63, wid = tid >> 6;
  const int wm = wid >> 1, wn = wid & 1;
  const size_t m0 = (size_t)blockIdx.x * 128;
  const int isbf = (ACT == 0) ? *flag : 1;

  floatx4 acc[4][8];
#pragma unroll
  for (int i = 0; i < 4; ++i)
#pragma unroll
    for (int j = 0; j < 8; ++j) acc[i][j] = (floatx4){0.f, 0.f, 0.f, 0.f};

  const int r0 = tid >> 2;          // 0..63 (manual staging row)
  const int c8 = (tid & 3) * 8;     // 0,8,16,24 (manual staging col group)
  const int lr = lane >> 2;         // 0..15 (lds-dma row in 16-row group)
  const int lc = (lane & 3) * 8;    // lds-dma col group (shorts)
  const int fr = lane & 15, q = lane >> 4;

  for (int kc = 0; kc < 8; ++kc) {
    const int k0 = kc * 32;
    __syncthreads();
    if (ACT == 0) {
      if (isbf) {
        const u16* Ab = (const u16*)Ag;
#pragma unroll
        for (int i = 0; i < 2; ++i)
          gload_lds16(Ab + (m0 + wid*32 + i*16 + lr)*256 + k0 + lc,
                      sA + (wid*32 + i*16)*32);
      } else {
        const float* Af = (const float*)Ag;
#pragma unroll
        for (int rr = 0; rr < 2; ++rr) {
          const int r = r0 + rr*64;
          float4 p0 = *(const float4*)(Af + (m0 + r)*256 + k0 + c8);
          float4 p1 = *(const float4*)(Af + (m0 + r)*256 + k0 + c8 + 4);
          u16 ov[8];
          ov[0]=f2bf(p0.x); ov[1]=f2bf(p0.y); ov[2]=f2bf(p0.z); ov[3]=f2bf(p0.w);
          ov[4]=f2bf(p1.x); ov[5]=f2bf(p1.y); ov[6]=f2bf(p1.z); ov[7]=f2bf(p1.w);
          *(uint4*)(sA + r*32 + c8) = *(const uint4*)ov;
        }
      }
    } else {
      const u16* Ab = (const u16*)Ag;
      float scv[8], shv[8];
#pragma unroll
      for (int j = 0; j < 8; ++j) { scv[j] = fscale[k0 + c8 + j]; shv[j] = fshift[k0 + c8 + j]; }
#pragma unroll
      for (int rr = 0; rr < 2; ++rr) {
        const int r = r0 + rr*64;
        uint4 pk = *(const uint4*)(Ab + (m0 + r)*256 + k0 + c8);
        const u16* us = (const u16*)&pk;
        u16 ov[8];
#pragma unroll
        for (int j = 0; j < 8; ++j) {
          float f = bf2f(us[j]);
          f = fmaxf(0.f, fmaf(f, scv[j], shv[j]));
          ov[j] = f2bf(f);
        }
        *(uint4*)(sA + r*32 + c8) = *(const uint4*)ov;
      }
    }
#pragma unroll
    for (int i = 0; i < 4; ++i)
      gload_lds16(Bt + (wid*64 + i*16 + lr)*256 + k0 + lc,
                  sB + (wid*64 + i*16)*32);
    __syncthreads();

    short8 a[4], b[8];
#pragma unroll
    for (int mf = 0; mf < 4; ++mf) a[mf] = *(const short8*)(sA + (wm*64 + mf*16 + fr)*32 + q*8);
#pragma unroll
    for (int nf = 0; nf < 8; ++nf) b[nf] = *(const short8*)(sB + (wn*128 + nf*16 + fr)*32 + q*8);
#pragma unroll
    for (int mf = 0; mf < 4; ++mf)
#pragma unroll
      for (int nf = 0; nf < 8; ++nf)
        acc[mf][nf] = __builtin_amdgcn_mfma_f32_16x16x32_bf16(a[mf], b[nf], acc[mf][nf], 0, 0, 0);
  }

#pragma unroll
  for (int mf = 0; mf < 4; ++mf)
#pragma unroll
    for (int nf = 0; nf < 8; ++nf)
#pragma unroll
      for (int r = 0; r < 4; ++r) {
        const size_t row = m0 + wm*64 + mf*16 + q*4 + r;
        const int col = wn*128 + nf*16 + fr;
        T[row*256 + col] = f2bf(acc[mf][nf][r]);
      }
}

// ---- per-graph aggregation H = Ahat @ T + b (IN-PLACE: H == T), BN stats ----
__global__ __launch_bounds__(256) void agg_kernel(const u16* __restrict__ T,
    const void* __restrict__ bias, u16* __restrict__ H, float* __restrict__ repl,
    const int* __restrict__ flag)
{
  const int g = blockIdx.x, c = threadIdx.x;
  const int isbf = *flag;
  const u16* tg = T + (size_t)g * (33*256);
  u16* hg = H + (size_t)g * (33*256);
  float acc[33];
#pragma unroll
  for (int d = 0; d < 33; ++d) acc[d] = 0.f;
#pragma unroll
  for (int s = 0; s < 33; ++s) {
    float v = bf2f(tg[s*256 + c]) * DINV[s];
    acc[s] += v;                          // self loop
#pragma unroll
    for (int i = 0; i < NBCNT[s]; ++i) acc[NBR[s][i]] += v;
  }
  const float bv = ldin(bias, c, isbf);
  float s1 = 0.f, s2 = 0.f;
#pragma unroll
  for (int d = 0; d < 33; ++d) {
    float o = fmaf(acc[d], DINV[d], bv);
    hg[d*256 + c] = f2bf(o);
    s1 += o; s2 += o*o;
  }
  float* r1 = repl + (size_t)(g & 63) * 512;
  atomicAdd(r1 + c, s1);
  atomicAdd(r1 + 256 + c, s2);
}

// ---- finalize BN stats -> scale/shift ----
__global__ __launch_bounds__(256) void statfin_kernel(const float* __restrict__ repl,
    const void* __restrict__ gamma, const void* __restrict__ beta, float* __restrict__ fs,
    const int* __restrict__ flag)
{
  const int c = threadIdx.x;
  const int isbf = *flag;
  float s1 = 0.f, s2 = 0.f;
  for (int r = 0; r < 64; ++r) { s1 += repl[r*512 + c]; s2 += repl[r*512 + 256 + c]; }
  const float inv = 1.f / (float)NN_TOT;
  const float mu = s1 * inv;
  const float var = s2 * inv - mu*mu;
  const float rs = rsqrtf(var + 1e-5f);
  const float sc = rs * ldin(gamma, c, isbf);
  fs[c] = sc;
  fs[256 + c] = ldin(beta, c, isbf) - mu * sc;
}

// ---- fused layer3 + mean-pool + classifier ----
__global__ __launch_bounds__(256) void final_kernel(const u16* __restrict__ H,
    const float* __restrict__ fs, const float* __restrict__ wq,
    const float* __restrict__ bq, void* __restrict__ outp,
    const int* __restrict__ flag)
{
  const int g = blockIdx.x, c = threadIdx.x;
  const int isbf = *flag;
  const float sc = fs[c], sh = fs[256 + c];
  const u16* hg = H + (size_t)g * (33*256);
  float v = 0.f;
#pragma unroll
  for (int s = 0; s < 33; ++s) {
    float a = DINV[s];
#pragma unroll
    for (int i = 0; i < NBCNT[s]; ++i) a += DINV[NBR[s][i]];
    const float w = DINV[s] * a * (1.f/33.f);   // column-sum of Ahat / 33
    float x = bf2f(hg[s*256 + c]);
    x = fmaxf(0.f, fmaf(x, sc, sh));
    v += w * x;
  }
  float p0 = v*wq[c*4+0], p1 = v*wq[c*4+1], p2 = v*wq[c*4+2], p3 = v*wq[c*4+3];
#pragma unroll
  for (int off = 32; off; off >>= 1) {
    p0 += __shfl_xor(p0, off);
    p1 += __shfl_xor(p1, off);
    p2 += __shfl_xor(p2, off);
    p3 += __shfl_xor(p3, off);
  }
  __shared__ float sred[4][4];
  const int lane = c & 63, wid = c >> 6;
  if (lane == 0) { sred[wid][0]=p0; sred[wid][1]=p1; sred[wid][2]=p2; sred[wid][3]=p3; }
  __syncthreads();
  if (c < 4) {
    float r = sred[0][c] + sred[1][c] + sred[2][c] + sred[3][c] + bq[c];
    if (isbf) ((u16*)outp)[(size_t)g*4 + c] = f2bf(r);
    else      ((float*)outp)[(size_t)g*4 + c] = r;
  }
}

extern "C" void kernel_launch(void* const* d_in, const int* in_sizes, int n_in,
                              void* d_out, int out_size, void* d_ws, size_t ws_size,
                              hipStream_t stream)
{
  const void* x   = d_in[0];
  const void* w0  = d_in[1];
  const void* b0  = d_in[2];
  const void* g0  = d_in[3];
  const void* be0 = d_in[4];
  const void* w1  = d_in[5];
  const void* b1  = d_in[6];
  const void* g1  = d_in[7];
  const void* be1 = d_in[8];
  const void* w2  = d_in[9];
  const void* b2  = d_in[10];
  const void* g2  = d_in[11];
  const void* be2 = d_in[12];
  const void* wh  = d_in[13];
  const void* bh  = d_in[14];
  const void* wc  = d_in[15];
  const void* bc  = d_in[16];

  // Workspace: 66.8 MB total.
  char* ws = (char*)d_ws;
  float* wq   = (float*)(ws + 0);          // 1024 f
  float* bq   = (float*)(ws + 4096);       // 4 f
  float* fs   = (float*)(ws + 4608);       // 3 * 512 f
  int*   flag = (int*)  (ws + 12288);      // dtype flag
  float* repl = (float*)(ws + 16384);      // 3 * 64 * 512 f
  u16*   Wt   = (u16*)  (ws + 409600);     // 3 * 65536 bf16
  u16*   A    = (u16*)  (ws + 802816);     // 135168*256 bf16 (ends at 70,008,832)
  (void)in_sizes; (void)n_in; (void)out_size; (void)ws_size;

  detect_kernel<<<1, 256, 0, stream>>>((const u16*)x, flag);
  transpose_kernel<<<48, 256, 0, stream>>>(w0, w1, w2, Wt, flag);
  init_kernel<<<65, 256, 0, stream>>>(wh, bh, wc, bc, wq, bq, repl, flag);

  // layer 0
  gemm_kernel<0><<<1056, 256, 0, stream>>>(x, Wt, nullptr, nullptr, A, flag);
  agg_kernel<<<4096, 256, 0, stream>>>(A, b0, A, repl, flag);
  statfin_kernel<<<1, 256, 0, stream>>>(repl, g0, be0, fs, flag);
  // layer 1 (in-place GEMM)
  gemm_kernel<1><<<1056, 256, 0, stream>>>(A, Wt + 65536, fs, fs + 256, A, flag);
  agg_kernel<<<4096, 256, 0, stream>>>(A, b1, A, repl + 32768, flag);
  statfin_kernel<<<1, 256, 0, stream>>>(repl + 32768, g1, be1, fs + 512, flag);
  // layer 2 (in-place GEMM)
  gemm_kernel<1><<<1056, 256, 0, stream>>>(A, Wt + 131072, fs + 512, fs + 768, A, flag);
  agg_kernel<<<4096, 256, 0, stream>>>(A, b2, A, repl + 65536, flag);
  statfin_kernel<<<1, 256, 0, stream>>>(repl + 65536, g2, be2, fs + 1024, flag);
  // layer 3 + pool + classifier (folded)
  final_kernel<<<4096, 256, 0, stream>>>(A, fs + 1024, wq, bq, d_out, flag);
}